// Round 2
// baseline (343.755 us; speedup 1.0000x reference)
//
#include <hip/hip_runtime.h>

#define TDIM 8192
#define NB 8
#define CD 512
#define SCALE 0.125f

typedef unsigned int u32;
typedef unsigned short u16;
typedef __bf16 bf16;
typedef bf16 bf16x8 __attribute__((ext_vector_type(8)));
typedef float f32x4 __attribute__((ext_vector_type(4)));
typedef u16 u16x4 __attribute__((ext_vector_type(4)));
typedef u16 u16x8 __attribute__((ext_vector_type(8)));

__device__ __forceinline__ u16 f2bf(float f) {
  u32 u = __float_as_uint(f);
  return (u16)((u + 0x7FFFu + ((u >> 16) & 1u)) >> 16);
}

__device__ __forceinline__ void gload16(const void* g, void* l) {
  __builtin_amdgcn_global_load_lds((const __attribute__((address_space(1))) u32*)g,
                                   (__attribute__((address_space(3))) u32*)l, 16, 0, 0);
}

// ---------------- K0: transpose + cast q: [b][c][t] f32 -> qT [b][t][c] bf16 ----------------
__global__ __launch_bounds__(256) void k_tq(const float* __restrict__ q, u16* __restrict__ qT) {
  __shared__ float tile[64][65];
  const int b = blockIdx.z, cb = blockIdx.y * 64, tb = blockIdx.x * 64;
  const int tid = threadIdx.x, r = tid >> 2, qd = tid & 3;
  const float* src = q + ((size_t)(b * CD + cb + r)) * TDIM + tb;
#pragma unroll
  for (int j = 0; j < 4; ++j) {
    const float4 v = *(const float4*)(src + j * 16 + qd * 4);
    tile[r][j * 16 + qd * 4 + 0] = v.x;
    tile[r][j * 16 + qd * 4 + 1] = v.y;
    tile[r][j * 16 + qd * 4 + 2] = v.z;
    tile[r][j * 16 + qd * 4 + 3] = v.w;
  }
  __syncthreads();
  u16x8 o0, o1;
#pragma unroll
  for (int i = 0; i < 8; ++i) o0[i] = f2bf(tile[qd * 16 + i][r]);
#pragma unroll
  for (int i = 0; i < 8; ++i) o1[i] = f2bf(tile[qd * 16 + 8 + i][r]);
  u16* dst = qT + ((size_t)b * TDIM + tb + r) * CD + cb + qd * 16;
  *(u16x8*)dst = o0;
  *(u16x8*)(dst + 8) = o1;
}

// ---------------- cast weights: Wq (512x512) ++ Wkv (1024x512) -> Wall bf16 ----------------
__global__ __launch_bounds__(256) void k_cast_w(const float* __restrict__ Wq, const float* __restrict__ Wkv,
                                                u16* __restrict__ Wall) {
  const int idx = (blockIdx.x * 256 + threadIdx.x) * 4;
  float4 v;
  if (idx < 512 * 512) v = *(const float4*)(Wq + idx);
  else                 v = *(const float4*)(Wkv + (idx - 512 * 512));
  u16x4 p;
  p[0] = f2bf(v.x); p[1] = f2bf(v.y); p[2] = f2bf(v.z); p[3] = f2bf(v.w);
  *(u16x4*)(Wall + idx) = p;
}

// ---------------- shared NT GEMM core: 128x128 tile, BK=64, double-buffered 2-phase ----------------
// A[m][k], B[n][k], both k-contiguous bf16, K=512. LDS 16B-chunk XOR swizzle (pre-swizzled global src).
// LDS layout: [buf0: A 16KB | B 16KB][buf1: A 16KB | B 16KB] = 64KB.
__device__ __forceinline__ void stage_tile(const u16* __restrict__ Abase, const u16* __restrict__ Bbase,
                                           char* Ad, char* Bd, int w, int rr, int ch, int kt) {
#pragma unroll
  for (int i = 0; i < 4; ++i) {
    const int row = w * 32 + i * 8 + rr;           // row&7 == rr
    const size_t goff = (size_t)row * CD + kt * 64 + ((ch ^ rr) << 3);
    gload16(Abase + goff, Ad + w * 4096 + i * 1024);
    gload16(Bbase + goff, Bd + w * 4096 + i * 1024);
  }
}

__device__ __forceinline__ void gemm_core(const u16* __restrict__ Abase, const u16* __restrict__ Bbase,
                                          u16* SM, f32x4 (&acc)[4][4]) {
  char* lds = (char*)SM;
  const int tid = threadIdx.x;
  const int lane = tid & 63;
  const int w = tid >> 6;
  const int wr = w >> 1, wc = w & 1;
  const int rr = lane >> 3;   // 0..7
  const int ch = lane & 7;    // 16B chunk within 128B row
  const int lo16 = lane & 15, hi4 = lane >> 4;
  stage_tile(Abase, Bbase, lds, lds + 16384, w, rr, ch, 0);
  __syncthreads();            // drain prologue stage
#pragma unroll 1
  for (int kt = 0; kt < 8; ++kt) {
    const int cur = kt & 1;
    char* Ac = lds + cur * 32768;
    char* Bc = Ac + 16384;
    if (kt < 7) {             // issue next-tile loads BEFORE compute; they drain at end-of-iter barrier
      char* An = lds + (cur ^ 1) * 32768;
      stage_tile(Abase, Bbase, An, An + 16384, w, rr, ch, kt + 1);
    }
    __builtin_amdgcn_sched_barrier(0);   // pin: stage-issue stays above compute
#pragma unroll
    for (int ks = 0; ks < 2; ++ks) {
      bf16x8 av[4], bv[4];
#pragma unroll
      for (int am = 0; am < 4; ++am) {
        const int rowA = wr * 64 + am * 16 + lo16;
        av[am] = *(const bf16x8*)(Ac + rowA * 128 + ((ks * 64 + hi4 * 16) ^ ((rowA & 7) << 4)));
      }
#pragma unroll
      for (int an = 0; an < 4; ++an) {
        const int rowB = wc * 64 + an * 16 + lo16;
        bv[an] = *(const bf16x8*)(Bc + rowB * 128 + ((ks * 64 + hi4 * 16) ^ ((rowB & 7) << 4)));
      }
#pragma unroll
      for (int am = 0; am < 4; ++am)
#pragma unroll
        for (int an = 0; an < 4; ++an)
          acc[am][an] = __builtin_amdgcn_mfma_f32_16x16x32_bf16(av[am], bv[an], acc[am][an], 0, 0, 0);
    }
    __syncthreads();          // drains vmcnt(0): next-tile stage complete, this-tile reads done
  }
}

// ---------------- K1: proj GEMM [1536x512]@[512x8192] per batch, fused epilogues ----------------
// 1D grid, XCD-bijective swizzle: 6144 blocks = 8 XCD x 768; one batch per XCD; the 12 mt-blocks
// sharing a qT B-tile are consecutive within an XCD chunk -> B-tile fetched once per XCD L2.
__global__ __launch_bounds__(256) void k_proj(const u16* __restrict__ Wall, const u16* __restrict__ qT,
                                              u16* __restrict__ qhT, u16* __restrict__ ek,
                                              u16* __restrict__ vb, float* __restrict__ rowsum) {
  __shared__ u16 SMEM[32768];   // 64 KB: dbuf staging, epilogue reuses first 32 KB
  const int lid = blockIdx.x;
  const int wg = (lid & 7) * 768 + (lid >> 3);
  const int mt = wg % 12, nt = (wg / 12) & 63, b = wg / 768;
  const int row0 = mt * 128, t0 = nt * 128;
  f32x4 acc[4][4] = {};
  gemm_core(Wall + (size_t)row0 * CD, qT + ((size_t)b * TDIM + t0) * CD, SMEM, acc);
  const int tid = threadIdx.x, lane = tid & 63, w = tid >> 6;
  const int wr = w >> 1, wc = w & 1, lo16 = lane & 15, hi4 = lane >> 4;
  char* lds = (char*)SMEM;
  float e[4][4][4];
  if (row0 < 512) {
    // ---- qh path: wave owns one full head (64 rows). softmax over rows per column, *SCALE.
#pragma unroll
    for (int am = 0; am < 4; ++am)
#pragma unroll
      for (int an = 0; an < 4; ++an)
#pragma unroll
        for (int r2 = 0; r2 < 4; ++r2) e[am][an][r2] = __expf(acc[am][an][r2]);
#pragma unroll
    for (int an = 0; an < 4; ++an) {
      float s = 0.f;
#pragma unroll
      for (int am = 0; am < 4; ++am)
#pragma unroll
        for (int r2 = 0; r2 < 4; ++r2) s += e[am][an][r2];
      s += __shfl_xor(s, 16);
      s += __shfl_xor(s, 32);
      const float inv = SCALE / s;
#pragma unroll
      for (int am = 0; am < 4; ++am)
#pragma unroll
        for (int r2 = 0; r2 < 4; ++r2) e[am][an][r2] *= inv;
    }
    // transposed LDS tile [t 128][c 128] bf16, 16B-gran XOR swizzle
#pragma unroll
    for (int am = 0; am < 4; ++am)
#pragma unroll
      for (int an = 0; an < 4; ++an) {
        const int tl = wc * 64 + an * 16 + lo16;
        const int cb2 = (wr * 64 + am * 16 + hi4 * 4) * 2;
        u16x4 p;
#pragma unroll
        for (int r2 = 0; r2 < 4; ++r2) p[r2] = f2bf(e[am][an][r2]);
        *(u16x4*)(lds + tl * 256 + ((cb2 & ~15) ^ ((tl & 7) << 4)) + (cb2 & 8)) = p;
      }
    __syncthreads();
#pragma unroll
    for (int pp = 0; pp < 8; ++pp) {
      const int tr = pp * 16 + (tid >> 4), chk = tid & 15;
      const uint4 val = *(const uint4*)(lds + tr * 256 + ((chk * 16) ^ ((tr & 7) << 4)));
      *(uint4*)(qhT + ((size_t)b * TDIM + t0 + tr) * CD + row0 + chk * 8) = val;
    }
  } else {
    // ---- k path (exp + rowsum) or v path (plain)
    const bool isK = row0 < 1024;
    const int c0 = row0 - (isK ? 512 : 1024);
    if (isK) {
#pragma unroll
      for (int am = 0; am < 4; ++am)
#pragma unroll
        for (int an = 0; an < 4; ++an)
#pragma unroll
          for (int r2 = 0; r2 < 4; ++r2) e[am][an][r2] = __expf(acc[am][an][r2]);
#pragma unroll
      for (int am = 0; am < 4; ++am)
#pragma unroll
        for (int r2 = 0; r2 < 4; ++r2) {
          float s = e[am][0][r2] + e[am][1][r2] + e[am][2][r2] + e[am][3][r2];
          s += __shfl_xor(s, 1); s += __shfl_xor(s, 2);
          s += __shfl_xor(s, 4); s += __shfl_xor(s, 8);
          if (lo16 == 0)
            unsafeAtomicAdd(rowsum + b * CD + c0 + wr * 64 + am * 16 + hi4 * 4 + r2, s);
        }
    } else {
#pragma unroll
      for (int am = 0; am < 4; ++am)
#pragma unroll
        for (int an = 0; an < 4; ++an)
#pragma unroll
          for (int r2 = 0; r2 < 4; ++r2) e[am][an][r2] = acc[am][an][r2];
    }
    // natural LDS tile [c 128][t 128] bf16, 16B-gran XOR swizzle; 2B scattered ds_writes
#pragma unroll
    for (int am = 0; am < 4; ++am)
#pragma unroll
      for (int an = 0; an < 4; ++an) {
        const int tl2 = (wc * 64 + an * 16 + lo16) * 2;
#pragma unroll
        for (int r2 = 0; r2 < 4; ++r2) {
          const int cl = wr * 64 + am * 16 + hi4 * 4 + r2;
          *(u16*)(lds + cl * 256 + ((tl2 & ~15) ^ ((cl & 7) << 4)) + (tl2 & 15)) = f2bf(e[am][an][r2]);
        }
      }
    __syncthreads();
    u16* dstb = isK ? ek : vb;
#pragma unroll
    for (int pp = 0; pp < 8; ++pp) {
      const int cr = pp * 16 + (tid >> 4), chk = tid & 15;
      const uint4 val = *(const uint4*)(lds + cr * 256 + ((chk * 16) ^ ((cr & 7) << 4)));
      *(uint4*)(dstb + ((size_t)b * CD + c0 + cr) * TDIM + t0 + chk * 8) = val;
    }
  }
}

// ---------------- K2: ctx_raw[b][h][d][e] += sum_t ek[d,t]*v[e,t] ----------------
// Per-wave private double-buffered staging with counted vmcnt; red aliased on wave-0 dead buffer.
__device__ __forceinline__ void ctx_stage(const u16* __restrict__ ekb, const u16* __restrict__ vbb,
                                          char* dst, int rr, int ch, int tb) {
#pragma unroll
  for (int i = 0; i < 8; ++i) {
    const int row = i * 8 + rr;
    const size_t goff = (size_t)row * TDIM + tb + ((ch ^ rr) << 3);
    gload16(ekb + goff, dst + i * 1024);          // ek rows -> [0,8KB)
    gload16(vbb + goff, dst + 8192 + i * 1024);   // v rows  -> [8KB,16KB)
  }
}

__global__ __launch_bounds__(256) void k_ctx(const u16* __restrict__ ek, const u16* __restrict__ vb,
                                             float* __restrict__ ctx) {
  __shared__ u16 SM[65536];        // 128 KB: 4 waves x 2 bufs x (ek 8KB + v 8KB)
  float (*red)[64] = (float(*)[64])SM;   // 16KB alias on wave-0 buf0 (dead by reduce time)
  const int bh = blockIdx.y, tch = blockIdx.x;
  const int b = bh >> 3, h = bh & 7;
  const int tid = threadIdx.x, lane = tid & 63, w = tid >> 6;
  const int lo16 = lane & 15, hi4 = lane >> 4;
  char* wbase = (char*)SM + w * 32768;
  const u16* ekb = ek + ((size_t)(b * CD + h * 64)) * TDIM;
  const u16* vbb = vb + ((size_t)(b * CD + h * 64)) * TDIM;
  const int rr = lane >> 3, ch = lane & 7;
  f32x4 acc[4][4] = {};
  const int t00 = tch * 1024 + w * 256;
  ctx_stage(ekb, vbb, wbase, rr, ch, t00);
#pragma unroll 1
  for (int s = 0; s < 4; ++s) {
    char* curb = wbase + (s & 1) * 16384;
    if (s < 3) {
      ctx_stage(ekb, vbb, wbase + ((s & 1) ^ 1) * 16384, rr, ch, t00 + (s + 1) * 64);
      asm volatile("s_waitcnt vmcnt(16)" ::: "memory");   // prev stage's 16 loads done, next 16 in flight
    } else {
      asm volatile("s_waitcnt vmcnt(0)" ::: "memory");
    }
    __builtin_amdgcn_sched_barrier(0);
#pragma unroll
    for (int ks = 0; ks < 2; ++ks) {
      bf16x8 av[4], bv[4];
#pragma unroll
      for (int am = 0; am < 4; ++am) {
        const int rowA = am * 16 + lo16;
        av[am] = *(const bf16x8*)(curb + rowA * 128 + ((ks * 64 + hi4 * 16) ^ ((rowA & 7) << 4)));
      }
#pragma unroll
      for (int an = 0; an < 4; ++an) {
        const int rowB = an * 16 + lo16;
        bv[an] = *(const bf16x8*)(curb + 8192 + rowB * 128 + ((ks * 64 + hi4 * 16) ^ ((rowB & 7) << 4)));
      }
#pragma unroll
      for (int am = 0; am < 4; ++am)
#pragma unroll
        for (int an = 0; an < 4; ++an)
          acc[am][an] = __builtin_amdgcn_mfma_f32_16x16x32_bf16(av[am], bv[an], acc[am][an], 0, 0, 0);
    }
  }
  // deterministic cross-wave reduce (no LDS atomics, no zero-init needed)
  for (int ww = 0; ww < 4; ++ww) {
    if (w == ww) {
#pragma unroll
      for (int am = 0; am < 4; ++am)
#pragma unroll
        for (int an = 0; an < 4; ++an)
#pragma unroll
          for (int r2 = 0; r2 < 4; ++r2) {
            const int d = am * 16 + hi4 * 4 + r2, e2 = an * 16 + lo16;
            if (ww == 0) red[d][e2] = acc[am][an][r2];
            else         red[d][e2] += acc[am][an][r2];
          }
    }
    __syncthreads();
  }
  float* cdst = ctx + (size_t)bh * 4096;
#pragma unroll
  for (int i = 0; i < 16; ++i) {
    const int idx = tid + 256 * i;
    unsafeAtomicAdd(cdst + idx, (&red[0][0])[idx]);
  }
}

// ---------------- K2b: Weff[b][o][64h+d] = sum_e Wout[o][64h+e] * ctx[d][e] / rowsum[d] ----------------
__global__ __launch_bounds__(256) void k_weff(const float* __restrict__ Wout, const float* __restrict__ ctx,
                                              const float* __restrict__ rowsum, u16* __restrict__ Weff) {
  __shared__ float cn[64][65];
  __shared__ float rsin[64];
  const int bh = blockIdx.y, b = bh >> 3, h = bh & 7;
  const int o0 = blockIdx.x * 64;
  const int tid = threadIdx.x;
  if (tid < 64) rsin[tid] = 1.f / rowsum[b * CD + h * 64 + tid];
  __syncthreads();
  const float* csrc = ctx + (size_t)bh * 4096;
#pragma unroll
  for (int i = 0; i < 16; ++i) {
    const int idx = tid + 256 * i;
    cn[idx >> 6][idx & 63] = csrc[idx] * rsin[idx >> 6];
  }
  __syncthreads();
  const int o = o0 + (tid >> 2), dq = (tid & 3) * 16;
  const float* wrow = Wout + (size_t)o * CD + h * 64;
  float a[16] = {};
  for (int e2 = 0; e2 < 64; ++e2) {
    const float wv = wrow[e2];
#pragma unroll
    for (int i = 0; i < 16; ++i) a[i] += wv * cn[dq + i][e2];
  }
  u16x8 p0, p1;
#pragma unroll
  for (int i = 0; i < 8; ++i) { p0[i] = f2bf(a[i]); p1[i] = f2bf(a[8 + i]); }
  u16* dst = Weff + ((size_t)(b * CD + o)) * CD + h * 64 + dq;
  *(u16x8*)dst = p0;
  *(u16x8*)(dst + 8) = p1;
}

// ---------------- K3: final[b][o][t] = Weff[b] @ qhT + b_out ----------------
// 1D grid, XCD-bijective swizzle: 2048 blocks = 8 XCD x 256; one batch per XCD.
__global__ __launch_bounds__(256) void k_final(const u16* __restrict__ Weff, const u16* __restrict__ qhT,
                                               const float* __restrict__ bias, float* __restrict__ out) {
  __shared__ u16 SMEM[32768];   // 64 KB dbuf
  const int lid = blockIdx.x;
  const int wg = (lid & 7) * 256 + (lid >> 3);
  const int mt = wg & 3, nt = (wg >> 2) & 63, b = wg >> 8;
  const int row0 = mt * 128, t0 = nt * 128;
  f32x4 acc[4][4] = {};
  gemm_core(Weff + ((size_t)(b * CD + row0)) * CD, qhT + ((size_t)b * TDIM + t0) * CD, SMEM, acc);
  const int tid = threadIdx.x, lane = tid & 63, w = tid >> 6;
  const int wr = w >> 1, wc = w & 1, lo16 = lane & 15, hi4 = lane >> 4;
#pragma unroll
  for (int am = 0; am < 4; ++am)
#pragma unroll
    for (int r2 = 0; r2 < 4; ++r2) {
      const int o = row0 + wr * 64 + am * 16 + hi4 * 4 + r2;
      const float bo = bias[o];
      float* orow = out + ((size_t)(b * CD + o)) * TDIM + t0 + wc * 64 + lo16;
#pragma unroll
      for (int an = 0; an < 4; ++an)
        orow[an * 16] = acc[am][an][r2] + bo;
    }
}

extern "C" void kernel_launch(void* const* d_in, const int* in_sizes, int n_in,
                              void* d_out, int out_size, void* d_ws, size_t ws_size,
                              hipStream_t stream) {
  const float* q    = (const float*)d_in[0];
  const float* Wq   = (const float*)d_in[1];
  const float* Wkv  = (const float*)d_in[2];
  const float* Wout = (const float*)d_in[3];
  const float* bout = (const float*)d_in[4];
  float* out = (float*)d_out;
  char* ws = (char*)d_ws;
  const size_t SZ = (size_t)NB * CD * TDIM * 2;   // 64 MiB per bf16 [8][512][8192] buffer
  u16* qT  = (u16*)ws;
  u16* qhT = (u16*)(ws + SZ);
  u16* ek  = (u16*)(ws + 2 * SZ);
  u16* vb  = (u16*)(ws + 3 * SZ);
  char* base = ws + 4 * SZ;
  u16* Wall   = (u16*)base;                       // 1.5 MB
  float* ctx  = (float*)(base + (2u << 20));      // 1 MB
  float* rsum = (float*)(base + (3u << 20));      // 16 KB
  u16* Weff   = (u16*)(base + (4u << 20));        // 4 MB
  (void)in_sizes; (void)n_in; (void)out_size; (void)ws_size;

  hipMemsetAsync(base + (2u << 20), 0, 2u << 20, stream);  // zero ctx + rowsum accumulators
  k_tq    <<<dim3(128, 8, 8), 256, 0, stream>>>(q, qT);
  k_cast_w<<<dim3(768), 256, 0, stream>>>(Wq, Wkv, Wall);
  k_proj  <<<dim3(6144), 256, 0, stream>>>(Wall, qT, qhT, ek, vb, rsum);
  k_ctx   <<<dim3(8, 64), 256, 0, stream>>>(ek, vb, ctx);
  k_weff  <<<dim3(8, 64), 256, 0, stream>>>(Wout, ctx, rsum, Weff);
  k_final <<<dim3(2048), 256, 0, stream>>>(Weff, qhT, bout, out);
}

// Round 3
// 323.402 us; speedup vs baseline: 1.0629x; 1.0629x over previous
//
#include <hip/hip_runtime.h>

#define TDIM 8192
#define NB 8
#define CD 512
#define SCALE 0.125f

typedef unsigned int u32;
typedef unsigned short u16;
typedef __bf16 bf16;
typedef bf16 bf16x8 __attribute__((ext_vector_type(8)));
typedef float f32x4 __attribute__((ext_vector_type(4)));
typedef u16 u16x4 __attribute__((ext_vector_type(4)));
typedef u16 u16x8 __attribute__((ext_vector_type(8)));

__device__ __forceinline__ u16 f2bf(float f) {
  u32 u = __float_as_uint(f);
  return (u16)((u + 0x7FFFu + ((u >> 16) & 1u)) >> 16);
}

__device__ __forceinline__ void gload16(const void* g, void* l) {
  __builtin_amdgcn_global_load_lds((const __attribute__((address_space(1))) u32*)g,
                                   (__attribute__((address_space(3))) u32*)l, 16, 0, 0);
}

// ---------------- K0: transpose + cast q: [b][c][t] f32 -> qT [b][t][c] bf16 ----------------
__global__ __launch_bounds__(256) void k_tq(const float* __restrict__ q, u16* __restrict__ qT) {
  __shared__ float tile[64][65];
  const int b = blockIdx.z, cb = blockIdx.y * 64, tb = blockIdx.x * 64;
  const int tid = threadIdx.x, r = tid >> 2, qd = tid & 3;
  const float* src = q + ((size_t)(b * CD + cb + r)) * TDIM + tb;
#pragma unroll
  for (int j = 0; j < 4; ++j) {
    const float4 v = *(const float4*)(src + j * 16 + qd * 4);
    tile[r][j * 16 + qd * 4 + 0] = v.x;
    tile[r][j * 16 + qd * 4 + 1] = v.y;
    tile[r][j * 16 + qd * 4 + 2] = v.z;
    tile[r][j * 16 + qd * 4 + 3] = v.w;
  }
  __syncthreads();
  u16x8 o0, o1;
#pragma unroll
  for (int i = 0; i < 8; ++i) o0[i] = f2bf(tile[qd * 16 + i][r]);
#pragma unroll
  for (int i = 0; i < 8; ++i) o1[i] = f2bf(tile[qd * 16 + 8 + i][r]);
  u16* dst = qT + ((size_t)b * TDIM + tb + r) * CD + cb + qd * 16;
  *(u16x8*)dst = o0;
  *(u16x8*)(dst + 8) = o1;
}

// ---------------- cast weights: Wq (512x512) ++ Wkv (1024x512) -> Wall bf16 ----------------
__global__ __launch_bounds__(256) void k_cast_w(const float* __restrict__ Wq, const float* __restrict__ Wkv,
                                                u16* __restrict__ Wall) {
  const int idx = (blockIdx.x * 256 + threadIdx.x) * 4;
  float4 v;
  if (idx < 512 * 512) v = *(const float4*)(Wq + idx);
  else                 v = *(const float4*)(Wkv + (idx - 512 * 512));
  u16x4 p;
  p[0] = f2bf(v.x); p[1] = f2bf(v.y); p[2] = f2bf(v.z); p[3] = f2bf(v.w);
  *(u16x4*)(Wall + idx) = p;
}

// ============ 256x128 GEMM core, BK=64, 8 waves (4M x 2N, wave=64x64), ring-3 LDS, counted vmcnt ============
// A[m][k] (256 rows), B[n][k] (128 rows), k-contiguous bf16, K=512 (8 K-tiles).
// Ring buf b: A at b*49152 (32 KB), B at b*49152+32768 (16 KB). K-tile k lives in buf[k%3];
// k+2 staged into buf[(k+2)%3] (never the buffer being read). vmcnt(6) once per K-tile keeps
// exactly one K-tile's stage (6 loads/wave) in flight across barriers; vmcnt(0) only at kt=6.
__device__ __forceinline__ void stageA(const u16* __restrict__ A, char* buf, int w, int rr, int ch, int kt) {
#pragma unroll
  for (int i = 0; i < 4; ++i) {
    const int row = (w * 4 + i) * 8 + rr;          // row&7 == rr
    gload16(A + (size_t)row * CD + kt * 64 + ((ch ^ rr) << 3), buf + (w * 4 + i) * 1024);
  }
}
__device__ __forceinline__ void stageB(const u16* __restrict__ B, char* buf, int w, int rr, int ch, int kt) {
#pragma unroll
  for (int i = 0; i < 2; ++i) {
    const int row = (w * 2 + i) * 8 + rr;
    gload16(B + (size_t)row * CD + kt * 64 + ((ch ^ rr) << 3), buf + 32768 + (w * 2 + i) * 1024);
  }
}

__device__ __forceinline__ void gemm256(const u16* __restrict__ A, const u16* __restrict__ B,
                                        char* lds, f32x4 (&acc)[4][4]) {
  const int tid = threadIdx.x, lane = tid & 63, w = tid >> 6;
  const int wr = w >> 1, wc = w & 1;
  const int rr = lane >> 3, ch = lane & 7;
  const int lo16 = lane & 15, hi4 = lane >> 4;
  stageA(A, lds, w, rr, ch, 0);          stageB(B, lds, w, rr, ch, 0);
  stageA(A, lds + 49152, w, rr, ch, 1);  stageB(B, lds + 49152, w, rr, ch, 1);
  asm volatile("s_waitcnt vmcnt(6)" ::: "memory");   // K-tile 0 landed; K-tile 1 in flight
  __builtin_amdgcn_s_barrier();
#pragma unroll 1
  for (int kt = 0; kt < 8; ++kt) {
    char* bc = lds + (kt % 3) * 49152;
    char* bn = lds + ((kt + 2) % 3) * 49152;
#pragma unroll
    for (int ks = 0; ks < 2; ++ks) {
      bf16x8 av[4], bv[4];
#pragma unroll
      for (int am = 0; am < 4; ++am) {
        const int rowA = wr * 64 + am * 16 + lo16;
        av[am] = *(const bf16x8*)(bc + rowA * 128 + ((ks * 64 + hi4 * 16) ^ ((rowA & 7) << 4)));
      }
#pragma unroll
      for (int an = 0; an < 4; ++an) {
        const int rowB = wc * 64 + an * 16 + lo16;
        bv[an] = *(const bf16x8*)(bc + 32768 + rowB * 128 + ((ks * 64 + hi4 * 16) ^ ((rowB & 7) << 4)));
      }
      if (kt < 6) {
        if (ks == 0) stageA(A, bn, w, rr, ch, kt + 2);
        else         stageB(B, bn, w, rr, ch, kt + 2);
      }
      if (ks == 1) {
        if (kt < 6)       asm volatile("s_waitcnt vmcnt(6)" ::: "memory");  // prev K-tile fully landed
        else if (kt == 6) asm volatile("s_waitcnt vmcnt(0)" ::: "memory");  // last K-tile landed
      }
      __builtin_amdgcn_s_barrier();
      asm volatile("s_waitcnt lgkmcnt(0)" ::: "memory");
      __builtin_amdgcn_sched_barrier(0);
      __builtin_amdgcn_s_setprio(1);
#pragma unroll
      for (int am = 0; am < 4; ++am)
#pragma unroll
        for (int an = 0; an < 4; ++an)
          acc[am][an] = __builtin_amdgcn_mfma_f32_16x16x32_bf16(av[am], bv[an], acc[am][an], 0, 0, 0);
      __builtin_amdgcn_s_setprio(0);
      __builtin_amdgcn_s_barrier();
    }
  }
}

// ---------------- K1: proj GEMM [1536x512]@[512x8192] per batch, fused epilogues ----------------
// 3072 blocks = 8 XCD x 384; b = wg/384; within-XCD: 6 consecutive mt share one qT B-tile.
__global__ __launch_bounds__(512, 2) void k_proj(const u16* __restrict__ Wall, const u16* __restrict__ qT,
                                                 u16* __restrict__ qhT, u16* __restrict__ ek,
                                                 u16* __restrict__ vb, float* __restrict__ rowsum) {
  __shared__ __align__(16) char LDS[147456];   // 144 KB ring-3; epilogue reuses first 64 KB
  const int lid = blockIdx.x;
  const int wg = (lid & 7) * 384 + (lid >> 3);
  const int b = wg / 384, r = wg % 384;
  const int mt = r % 6, nt = r / 6;
  const int row0 = mt * 256, t0 = nt * 128;
  f32x4 acc[4][4] = {};
  gemm256(Wall + (size_t)row0 * CD, qT + ((size_t)b * TDIM + t0) * CD, LDS, acc);
  const int tid = threadIdx.x, lane = tid & 63, w = tid >> 6;
  const int wr = w >> 1, wc = w & 1, lo16 = lane & 15, hi4 = lane >> 4;
  char* lds = LDS;
  float e[4][4][4];
  if (row0 < 512) {
    // ---- qh path: wave owns head (row0/64 + wr): 64 rows. softmax over rows per column, *SCALE.
#pragma unroll
    for (int am = 0; am < 4; ++am)
#pragma unroll
      for (int an = 0; an < 4; ++an)
#pragma unroll
        for (int r2 = 0; r2 < 4; ++r2) e[am][an][r2] = __expf(acc[am][an][r2]);
#pragma unroll
    for (int an = 0; an < 4; ++an) {
      float s = 0.f;
#pragma unroll
      for (int am = 0; am < 4; ++am)
#pragma unroll
        for (int r2 = 0; r2 < 4; ++r2) s += e[am][an][r2];
      s += __shfl_xor(s, 16);
      s += __shfl_xor(s, 32);
      const float inv = SCALE / s;
#pragma unroll
      for (int am = 0; am < 4; ++am)
#pragma unroll
        for (int r2 = 0; r2 < 4; ++r2) e[am][an][r2] *= inv;
    }
    // transposed LDS tile [t 128][c 256] bf16 (64 KB), 16B-gran XOR swizzle
#pragma unroll
    for (int am = 0; am < 4; ++am)
#pragma unroll
      for (int an = 0; an < 4; ++an) {
        const int tl = wc * 64 + an * 16 + lo16;
        const int cb2 = (wr * 64 + am * 16 + hi4 * 4) * 2;
        u16x4 p;
#pragma unroll
        for (int r2 = 0; r2 < 4; ++r2) p[r2] = f2bf(e[am][an][r2]);
        *(u16x4*)(lds + tl * 512 + ((cb2 & ~15) ^ ((tl & 7) << 4)) + (cb2 & 8)) = p;
      }
    __syncthreads();
#pragma unroll
    for (int pp = 0; pp < 8; ++pp) {
      const int tr = pp * 16 + (tid >> 5), chk = tid & 31;
      const uint4 val = *(const uint4*)(lds + tr * 512 + ((chk * 16) ^ ((tr & 7) << 4)));
      *(uint4*)(qhT + ((size_t)b * TDIM + t0 + tr) * CD + row0 + chk * 8) = val;
    }
  } else {
    // ---- k path (exp + rowsum) or v path (plain)
    const bool isK = row0 < 1024;
    const int c0 = row0 - (isK ? 512 : 1024);
    if (isK) {
#pragma unroll
      for (int am = 0; am < 4; ++am)
#pragma unroll
        for (int an = 0; an < 4; ++an)
#pragma unroll
          for (int r2 = 0; r2 < 4; ++r2) e[am][an][r2] = __expf(acc[am][an][r2]);
#pragma unroll
      for (int am = 0; am < 4; ++am)
#pragma unroll
        for (int r2 = 0; r2 < 4; ++r2) {
          float s = e[am][0][r2] + e[am][1][r2] + e[am][2][r2] + e[am][3][r2];
          s += __shfl_xor(s, 1); s += __shfl_xor(s, 2);
          s += __shfl_xor(s, 4); s += __shfl_xor(s, 8);
          if (lo16 == 0)
            unsafeAtomicAdd(rowsum + b * CD + c0 + wr * 64 + am * 16 + hi4 * 4 + r2, s);
        }
    } else {
#pragma unroll
      for (int am = 0; am < 4; ++am)
#pragma unroll
        for (int an = 0; an < 4; ++an)
#pragma unroll
          for (int r2 = 0; r2 < 4; ++r2) e[am][an][r2] = acc[am][an][r2];
    }
    // natural LDS tile [c 256][t 128] bf16 (64 KB), 16B-gran XOR swizzle; 2B scattered ds_writes
#pragma unroll
    for (int am = 0; am < 4; ++am)
#pragma unroll
      for (int an = 0; an < 4; ++an) {
        const int tl2 = (wc * 64 + an * 16 + lo16) * 2;
#pragma unroll
        for (int r2 = 0; r2 < 4; ++r2) {
          const int cl = wr * 64 + am * 16 + hi4 * 4 + r2;
          *(u16*)(lds + cl * 256 + ((tl2 & ~15) ^ ((cl & 7) << 4)) + (tl2 & 15)) = f2bf(e[am][an][r2]);
        }
      }
    __syncthreads();
    u16* dstb = isK ? ek : vb;
#pragma unroll
    for (int pp = 0; pp < 8; ++pp) {
      const int cr = pp * 32 + (tid >> 4), chk = tid & 15;
      const uint4 val = *(const uint4*)(lds + cr * 256 + ((chk * 16) ^ ((cr & 7) << 4)));
      *(uint4*)(dstb + ((size_t)b * CD + c0 + cr) * TDIM + t0 + chk * 8) = val;
    }
  }
}

// ---------------- K2: ctx_raw[b][h][d][e] += sum_t ek[d,t]*v[e,t] ----------------
__device__ __forceinline__ void ctx_stage(const u16* __restrict__ ekb, const u16* __restrict__ vbb,
                                          char* dst, int rr, int ch, int tb) {
#pragma unroll
  for (int i = 0; i < 8; ++i) {
    const int row = i * 8 + rr;
    const size_t goff = (size_t)row * TDIM + tb + ((ch ^ rr) << 3);
    gload16(ekb + goff, dst + i * 1024);
    gload16(vbb + goff, dst + 8192 + i * 1024);
  }
}

__global__ __launch_bounds__(256) void k_ctx(const u16* __restrict__ ek, const u16* __restrict__ vb,
                                             float* __restrict__ ctx) {
  __shared__ u16 SM[65536];        // 128 KB: 4 waves x 2 bufs x (ek 8KB + v 8KB)
  float (*red)[64] = (float(*)[64])SM;
  const int bh = blockIdx.y, tch = blockIdx.x;
  const int b = bh >> 3, h = bh & 7;
  const int tid = threadIdx.x, lane = tid & 63, w = tid >> 6;
  const int lo16 = lane & 15, hi4 = lane >> 4;
  char* wbase = (char*)SM + w * 32768;
  const u16* ekb = ek + ((size_t)(b * CD + h * 64)) * TDIM;
  const u16* vbb = vb + ((size_t)(b * CD + h * 64)) * TDIM;
  const int rr = lane >> 3, ch = lane & 7;
  f32x4 acc[4][4] = {};
  const int t00 = tch * 1024 + w * 256;
  ctx_stage(ekb, vbb, wbase, rr, ch, t00);
#pragma unroll 1
  for (int s = 0; s < 4; ++s) {
    char* curb = wbase + (s & 1) * 16384;
    if (s < 3) {
      ctx_stage(ekb, vbb, wbase + ((s & 1) ^ 1) * 16384, rr, ch, t00 + (s + 1) * 64);
      asm volatile("s_waitcnt vmcnt(16)" ::: "memory");
    } else {
      asm volatile("s_waitcnt vmcnt(0)" ::: "memory");
    }
    __builtin_amdgcn_sched_barrier(0);
#pragma unroll
    for (int ks = 0; ks < 2; ++ks) {
      bf16x8 av[4], bv[4];
#pragma unroll
      for (int am = 0; am < 4; ++am) {
        const int rowA = am * 16 + lo16;
        av[am] = *(const bf16x8*)(curb + rowA * 128 + ((ks * 64 + hi4 * 16) ^ ((rowA & 7) << 4)));
      }
#pragma unroll
      for (int an = 0; an < 4; ++an) {
        const int rowB = an * 16 + lo16;
        bv[an] = *(const bf16x8*)(curb + 8192 + rowB * 128 + ((ks * 64 + hi4 * 16) ^ ((rowB & 7) << 4)));
      }
#pragma unroll
      for (int am = 0; am < 4; ++am)
#pragma unroll
        for (int an = 0; an < 4; ++an)
          acc[am][an] = __builtin_amdgcn_mfma_f32_16x16x32_bf16(av[am], bv[an], acc[am][an], 0, 0, 0);
    }
  }
  for (int ww = 0; ww < 4; ++ww) {
    if (w == ww) {
#pragma unroll
      for (int am = 0; am < 4; ++am)
#pragma unroll
        for (int an = 0; an < 4; ++an)
#pragma unroll
          for (int r2 = 0; r2 < 4; ++r2) {
            const int d = am * 16 + hi4 * 4 + r2, e2 = an * 16 + lo16;
            if (ww == 0) red[d][e2] = acc[am][an][r2];
            else         red[d][e2] += acc[am][an][r2];
          }
    }
    __syncthreads();
  }
  float* cdst = ctx + (size_t)bh * 4096;
#pragma unroll
  for (int i = 0; i < 16; ++i) {
    const int idx = tid + 256 * i;
    unsafeAtomicAdd(cdst + idx, (&red[0][0])[idx]);
  }
}

// ---------------- K2b: Weff[b][o][64h+d] = sum_e Wout[o][64h+e] * ctx[d][e] / rowsum[d] ----------------
__global__ __launch_bounds__(256) void k_weff(const float* __restrict__ Wout, const float* __restrict__ ctx,
                                              const float* __restrict__ rowsum, u16* __restrict__ Weff) {
  __shared__ float cn[64][65];
  __shared__ float rsin[64];
  const int bh = blockIdx.y, b = bh >> 3, h = bh & 7;
  const int o0 = blockIdx.x * 64;
  const int tid = threadIdx.x;
  if (tid < 64) rsin[tid] = 1.f / rowsum[b * CD + h * 64 + tid];
  __syncthreads();
  const float* csrc = ctx + (size_t)bh * 4096;
#pragma unroll
  for (int i = 0; i < 16; ++i) {
    const int idx = tid + 256 * i;
    cn[idx >> 6][idx & 63] = csrc[idx] * rsin[idx >> 6];
  }
  __syncthreads();
  const int o = o0 + (tid >> 2), dq = (tid & 3) * 16;
  const float* wrow = Wout + (size_t)o * CD + h * 64;
  float a[16] = {};
  for (int e2 = 0; e2 < 64; ++e2) {
    const float wv = wrow[e2];
#pragma unroll
    for (int i = 0; i < 16; ++i) a[i] += wv * cn[dq + i][e2];
  }
  u16x8 p0, p1;
#pragma unroll
  for (int i = 0; i < 8; ++i) { p0[i] = f2bf(a[i]); p1[i] = f2bf(a[8 + i]); }
  u16* dst = Weff + ((size_t)(b * CD + o)) * CD + h * 64 + dq;
  *(u16x8*)dst = p0;
  *(u16x8*)(dst + 8) = p1;
}

// ---------------- K3: final[b][o][t] = Weff[b] @ qhT + b_out ----------------
// 1024 blocks = 8 XCD x 128.
__global__ __launch_bounds__(512, 2) void k_final(const u16* __restrict__ Weff, const u16* __restrict__ qhT,
                                                  const float* __restrict__ bias, float* __restrict__ out) {
  __shared__ __align__(16) char LDS[147456];
  const int lid = blockIdx.x;
  const int wg = (lid & 7) * 128 + (lid >> 3);
  const int b = wg >> 7, r = wg & 127;
  const int mt = r & 1, nt = r >> 1;
  const int row0 = mt * 256, t0 = nt * 128;
  f32x4 acc[4][4] = {};
  gemm256(Weff + ((size_t)(b * CD + row0)) * CD, qhT + ((size_t)b * TDIM + t0) * CD, LDS, acc);
  const int tid = threadIdx.x, lane = tid & 63, w = tid >> 6;
  const int wr = w >> 1, wc = w & 1, lo16 = lane & 15, hi4 = lane >> 4;
#pragma unroll
  for (int am = 0; am < 4; ++am)
#pragma unroll
    for (int r2 = 0; r2 < 4; ++r2) {
      const int o = row0 + wr * 64 + am * 16 + hi4 * 4 + r2;
      const float bo = bias[o];
      float* orow = out + ((size_t)(b * CD + o)) * TDIM + t0 + wc * 64 + lo16;
#pragma unroll
      for (int an = 0; an < 4; ++an)
        orow[an * 16] = acc[am][an][r2] + bo;
    }
}

extern "C" void kernel_launch(void* const* d_in, const int* in_sizes, int n_in,
                              void* d_out, int out_size, void* d_ws, size_t ws_size,
                              hipStream_t stream) {
  const float* q    = (const float*)d_in[0];
  const float* Wq   = (const float*)d_in[1];
  const float* Wkv  = (const float*)d_in[2];
  const float* Wout = (const float*)d_in[3];
  const float* bout = (const float*)d_in[4];
  float* out = (float*)d_out;
  char* ws = (char*)d_ws;
  const size_t SZ = (size_t)NB * CD * TDIM * 2;   // 64 MiB per bf16 [8][512][8192] buffer
  u16* qT  = (u16*)ws;
  u16* qhT = (u16*)(ws + SZ);
  u16* ek  = (u16*)(ws + 2 * SZ);
  u16* vb  = (u16*)(ws + 3 * SZ);
  char* base = ws + 4 * SZ;
  u16* Wall   = (u16*)base;                       // 1.5 MB
  float* ctx  = (float*)(base + (2u << 20));      // 1 MB
  float* rsum = (float*)(base + (3u << 20));      // 16 KB
  u16* Weff   = (u16*)(base + (4u << 20));        // 4 MB
  (void)in_sizes; (void)n_in; (void)out_size; (void)ws_size;

  hipMemsetAsync(base + (2u << 20), 0, 2u << 20, stream);  // zero ctx + rowsum accumulators
  k_tq    <<<dim3(128, 8, 8), 256, 0, stream>>>(q, qT);
  k_cast_w<<<dim3(768), 256, 0, stream>>>(Wq, Wkv, Wall);
  k_proj  <<<dim3(3072), 512, 0, stream>>>(Wall, qT, qhT, ek, vb, rsum);
  k_ctx   <<<dim3(8, 64), 256, 0, stream>>>(ek, vb, ctx);
  k_weff  <<<dim3(8, 64), 256, 0, stream>>>(Wout, ctx, rsum, Weff);
  k_final <<<dim3(2048 / 2), 512, 0, stream>>>(Weff, qhT, bout, out);
}